// Round 12
// baseline (2835.588 us; speedup 1.0000x reference)
//
#include <hip/hip_runtime.h>
#include <hip/hip_bf16.h>

// Problem dims
#define BSZ 32
#define SSZ 512
#define ISZ 512
#define HSZ 512
// ws layout (bytes)
#define XB_OFF   0ull                       // [S][64 kc][32 b][8] ushort (bf16 bits) = 16 MB
#define HEX_OFF  (16ull << 20)              // [2 dir][2 buf][64 kc][32 b][8] ushort = 128 KB
#define CTR_OFF  (HEX_OFF + (128ull << 10)) // flags: [dir] stride 2048 dwords; tab at dword 4096

typedef __attribute__((ext_vector_type(8)))  short short8;
typedef __attribute__((ext_vector_type(4)))  float f32x4;
typedef __attribute__((ext_vector_type(4)))  unsigned short us4;
typedef __attribute__((ext_vector_type(4)))  int i32x4;

__device__ __forceinline__ unsigned short f2bf(float f) {
    union { float f; unsigned u; } v; v.f = f;
    unsigned r = v.u + 0x7fffu + ((v.u >> 16) & 1u);   // RNE
    return (unsigned short)(r >> 16);
}

__device__ __forceinline__ float sigf(float x) { return 1.0f / (1.0f + __expf(-x)); }
__device__ __forceinline__ float tanhfast(float x) {
    float a = fabsf(x);
    float e = __expf(-2.0f * a);
    float t = (1.0f - e) / (1.0f + e);
    return x < 0.0f ? -t : t;
}

// X [B][S][I] fp32 -> Xb [t][kc][b][8] bf16-bits (MFMA A-fragment friendly layout)
__global__ void k_xpose(const float* __restrict__ X, unsigned short* __restrict__ Xb) {
    int idx = blockIdx.x * 256 + threadIdx.x;     // 2^21 threads total
    int i4 = idx & 127;                           // float4 index along I
    int t  = (idx >> 7) & 511;
    int b  = idx >> 16;
    float4 v = reinterpret_cast<const float4*>(X)[idx];
    us4 o = { f2bf(v.x), f2bf(v.y), f2bf(v.z), f2bf(v.w) };
    *reinterpret_cast<us4*>(Xb + (size_t)t * 16384 + (size_t)(i4 >> 1) * 256 + b * 8 + (i4 & 1) * 4) = o;
}

// R9 structure + SPLIT WAIT: h-wave `sub` polls only its 16 producer flags
// (blocks [16*sub, 16*sub+16) write h-cols [256*sub, 256*sub+256) = exactly the
// K-half this wave loads). sync#1 still joins both waves, so the block's step-s
// h-store transitively requires ALL 32 flags >= s — R9's 2-deep-ring safety holds.
// Publish edge (drain -> barrier -> tid0 single flag store) byte-identical to R9.
__launch_bounds__(256, 1)
__global__ void k_bilstm(const float* __restrict__ Wih_f, const float* __restrict__ Whh_f,
                         const float* __restrict__ bih_f, const float* __restrict__ bhh_f,
                         const float* __restrict__ Wih_b, const float* __restrict__ Whh_b,
                         const float* __restrict__ bih_b, const float* __restrict__ bhh_b,
                         const unsigned short* __restrict__ Xb,
                         unsigned short* h_ex, unsigned* flags, float* __restrict__ out)
{
    const int tid = threadIdx.x;
    const int grp = blockIdx.x & 7;
    if (grp >= 2) return;                // 256 blocks: XCD0 = dir0, XCD1 = dir1
    const int dir = grp;
    const int p   = blockIdx.x >> 3;     // 0..31 : owns h-cols [16p, 16p+16)
    const int wv  = tid >> 6;
    const int ln  = tid & 63;
    const int kh  = wv >> 1;             // 0: x-projection, 1: h-recurrence
    const int sub = wv & 1;              // x: gate-pair ; h: K-half
    const int q   = ln >> 4;
    const int m15 = ln & 15;

    unsigned* tab = flags + 4096;
    {
        unsigned xcc;
        asm volatile("s_getreg_b32 %0, hwreg(20, 0, 32)" : "=s"(xcc));
        if (tid == 0)
            __hip_atomic_store(tab + dir * 32 + p, (xcc & 7u) + 1u,
                               __ATOMIC_RELAXED, __HIP_MEMORY_SCOPE_AGENT);
    }

    const float* Wih = dir ? Wih_b : Wih_f;
    const float* Whh = dir ? Whh_b : Whh_f;
    const float* bi  = dir ? bih_b : bih_f;
    const float* bh  = dir ? bhh_b : bhh_f;

    __shared__ float gates[3][32][67];   // 0: x (col-split), 1: h K-half0, 2: h K-half1
    __shared__ float cst[32][16];
    __shared__ float bias[64];
    __shared__ int   mode_sh;

    // ---- weights in registers for all 512 steps (128 VGPRs either role) ----
    short8 breg[32];
    if (kh == 0) {
        // x-wave: gate-pair sub (gates sub*2, sub*2+1), full K -> breg[ks*2+gg]
#pragma unroll
        for (int ks = 0; ks < 16; ++ks)
#pragma unroll
            for (int gg = 0; gg < 2; ++gg) {
                const float* wr = Wih + (size_t)((sub * 2 + gg) * 512 + p * 16 + m15) * 512
                                      + ks * 32 + q * 8;
                short8 bb;
#pragma unroll
                for (int j = 0; j < 8; ++j) bb[j] = (short)f2bf(wr[j]);
                breg[ks * 2 + gg] = bb;
            }
    } else {
        // h-wave: ALL 4 gates, K-half sub -> breg[ks*4+g], ks 0..7
#pragma unroll
        for (int ks = 0; ks < 8; ++ks)
#pragma unroll
            for (int g = 0; g < 4; ++g) {
                const float* wr = Whh + (size_t)(g * 512 + p * 16 + m15) * 512
                                      + sub * 256 + ks * 32 + q * 8;
                short8 bb;
#pragma unroll
                for (int j = 0; j < 8; ++j) bb[j] = (short)f2bf(wr[j]);
                breg[ks * 4 + g] = bb;
            }
    }

    if (tid < 64) {
        int c = tid;
        int gr = (c >> 4) * 512 + p * 16 + (c & 15);
        bias[c] = bi[gr] + bh[gr];
    }
    for (int i = tid; i < 512; i += 256) ((float*)cst)[i] = 0.0f;

    // ---- placement discovery (deadlock-free: every owner writes its slot) ----
    if (tid < 64) {
        const unsigned* tp = tab + dir * 32 + (tid & 31);
        unsigned v;
        do { v = __hip_atomic_load(tp, __ATOMIC_RELAXED, __HIP_MEMORY_SCOPE_AGENT); } while (v == 0u);
        unsigned ref = __shfl(v, 0);
        int same = (__ballot(v == ref) == ~0ull) ? 1 : 0;
        if (tid == 0) mode_sh = same;
    }
    __syncthreads();
    const int fast = mode_sh;

    unsigned* flg = flags + (size_t)dir * 2048;      // 32 dwords = 1 cache line per dir
    unsigned short* hexd = h_ex + (size_t)dir * 2 * 16384;

    int agent_poll = 0;

    for (int s = 0; s < 512; ++s) {
        const int t = dir ? (511 - s) : s;
        f32x4 acc[4][2];
#pragma unroll
        for (int g = 0; g < 4; ++g) { acc[g][0] = {0.f,0.f,0.f,0.f}; acc[g][1] = {0.f,0.f,0.f,0.f}; }

        if (kh == 0) {
            // ---- x-projection: no waiting ever; plain (L2-cacheable) loads ----
            const unsigned short* abase = Xb + (size_t)t * 16384;
#pragma unroll
            for (int ks = 0; ks < 16; ++ks) {
                const unsigned short* ap = abase + (size_t)(ks * 4 + q) * 256 + m15 * 8;
                short8 a0 = *reinterpret_cast<const short8*>(ap);
                short8 a1 = *reinterpret_cast<const short8*>(ap + 128);
                acc[0][0] = __builtin_amdgcn_mfma_f32_16x16x32_bf16(a0, breg[ks * 2 + 0], acc[0][0], 0, 0, 0);
                acc[1][0] = __builtin_amdgcn_mfma_f32_16x16x32_bf16(a0, breg[ks * 2 + 1], acc[1][0], 0, 0, 0);
                acc[0][1] = __builtin_amdgcn_mfma_f32_16x16x32_bf16(a1, breg[ks * 2 + 0], acc[0][1], 0, 0, 0);
                acc[1][1] = __builtin_amdgcn_mfma_f32_16x16x32_bf16(a1, breg[ks * 2 + 1], acc[1][1], 0, 0, 0);
            }
            // dump: plane 0, cols (sub*2+gg)*16 + m15
#pragma unroll
            for (int gg = 0; gg < 2; ++gg)
#pragma unroll
                for (int r = 0; r < 4; ++r) {
                    gates[0][q * 4 + r][(sub * 2 + gg) * 16 + m15]      = acc[gg][0][r];
                    gates[0][16 + q * 4 + r][(sub * 2 + gg) * 16 + m15] = acc[gg][1][r];
                }
        } else if (fast) {
            // ---- h-recurrence, XCD-local L2 path; K-half `sub` only (16KB) ----
            if (s > 0) {
                // SPLIT WAIT: only the 16 producers of this wave's K-half
                const unsigned* fp = flg + sub * 16 + (ln & 15);
                if (!agent_poll) {
                    int spins = 0;
                    for (;;) {
                        unsigned v;
                        asm volatile("global_load_dword %0, %1, off sc0\n\t"
                                     "s_waitcnt vmcnt(0)"
                                     : "=&v"(v) : "v"(fp) : "memory");
                        if (__ballot((int)(v >= (unsigned)s)) == ~0ull) break;
                        if (++spins > 20000) { agent_poll = 1; break; }
                    }
                }
                if (agent_poll) {
                    for (;;) {
                        unsigned v = __hip_atomic_load(fp, __ATOMIC_RELAXED, __HIP_MEMORY_SCOPE_AGENT);
                        if (__ballot((int)(v >= (unsigned)s)) == ~0ull) break;
                    }
                }
                asm volatile("" ::: "memory");
            }
            const unsigned short* ab = hexd + (size_t)((s + 1) & 1) * 16384 + sub * 8192;
            i32x4 A0[8], A1[8];
#pragma unroll
            for (int ks = 0; ks < 8; ++ks) {
                const unsigned short* ap = ab + (size_t)(ks * 4 + q) * 256 + m15 * 8;
                asm volatile("global_load_dwordx4 %0, %2, off sc0\n\t"
                             "global_load_dwordx4 %1, %3, off sc0"
                             : "=&v"(A0[ks]), "=&v"(A1[ks])
                             : "v"(ap), "v"(ap + 128) : "memory");
            }
#pragma unroll
            for (int ks = 0; ks < 8; ++ks) {
                asm volatile("s_waitcnt vmcnt(%0)" :: "n"(14 - 2 * ks) : "memory");
                __builtin_amdgcn_sched_barrier(0);
                short8 a0 = __builtin_bit_cast(short8, A0[ks]);
                short8 a1 = __builtin_bit_cast(short8, A1[ks]);
#pragma unroll
                for (int g = 0; g < 4; ++g) {
                    acc[g][0] = __builtin_amdgcn_mfma_f32_16x16x32_bf16(a0, breg[ks * 4 + g], acc[g][0], 0, 0, 0);
                    acc[g][1] = __builtin_amdgcn_mfma_f32_16x16x32_bf16(a1, breg[ks * 4 + g], acc[g][1], 0, 0, 0);
                }
            }
            // dump: K-partial plane 1+sub, full 64-col width
#pragma unroll
            for (int g = 0; g < 4; ++g)
#pragma unroll
                for (int r = 0; r < 4; ++r) {
                    gates[1 + sub][q * 4 + r][g * 16 + m15]      = acc[g][0][r];
                    gates[1 + sub][16 + q * 4 + r][g * 16 + m15] = acc[g][1][r];
                }
        } else {
            // ---- h-recurrence, fallback agent/LLC path (split wait identically) ----
            if (s > 0) {
                const unsigned* fp = flg + sub * 16 + (ln & 15);
                for (;;) {
                    unsigned v = __hip_atomic_load(fp, __ATOMIC_RELAXED, __HIP_MEMORY_SCOPE_AGENT);
                    if (__ballot((int)(v >= (unsigned)s)) == ~0ull) break;
                }
                asm volatile("" ::: "memory");
            }
            const unsigned* abase = reinterpret_cast<const unsigned*>(
                hexd + (size_t)((s + 1) & 1) * 16384 + sub * 8192);
#pragma unroll
            for (int ks = 0; ks < 8; ++ks) {
                const unsigned* ap = abase + ((ks * 4 + q) * 256 + m15 * 8) / 2;
                union { short8 s8; unsigned u[4]; } ua0, ua1;
#pragma unroll
                for (int w = 0; w < 4; ++w) {
                    ua0.u[w] = __hip_atomic_load(ap + w,      __ATOMIC_RELAXED, __HIP_MEMORY_SCOPE_AGENT);
                    ua1.u[w] = __hip_atomic_load(ap + 64 + w, __ATOMIC_RELAXED, __HIP_MEMORY_SCOPE_AGENT);
                }
#pragma unroll
                for (int g = 0; g < 4; ++g) {
                    acc[g][0] = __builtin_amdgcn_mfma_f32_16x16x32_bf16(ua0.s8, breg[ks * 4 + g], acc[g][0], 0, 0, 0);
                    acc[g][1] = __builtin_amdgcn_mfma_f32_16x16x32_bf16(ua1.s8, breg[ks * 4 + g], acc[g][1], 0, 0, 0);
                }
            }
#pragma unroll
            for (int g = 0; g < 4; ++g)
#pragma unroll
                for (int r = 0; r < 4; ++r) {
                    gates[1 + sub][q * 4 + r][g * 16 + m15]      = acc[g][0][r];
                    gates[1 + sub][16 + q * 4 + r][g * 16 + m15] = acc[g][1][r];
                }
        }

        __syncthreads();   // sync#1: all three plane dumps visible (joins both half-waits)

        // ---- gate math: each thread handles (b, j0) and (b, j0+1); 3-plane sum ----
        int b  = tid >> 3;
        int j0 = (tid & 7) * 2;
        float hv01[2], cn01[2];
        {
#pragma unroll
            for (int u = 0; u < 2; ++u) {
                int j = j0 + u;
                float ig = gates[0][b][j]      + gates[1][b][j]      + gates[2][b][j]      + bias[j];
                float fg = gates[0][b][16 + j] + gates[1][b][16 + j] + gates[2][b][16 + j] + bias[16 + j];
                float gg = gates[0][b][32 + j] + gates[1][b][32 + j] + gates[2][b][32 + j] + bias[32 + j];
                float og = gates[0][b][48 + j] + gates[1][b][48 + j] + gates[2][b][48 + j] + bias[48 + j];
                float cn = sigf(fg) * cst[b][j] + sigf(ig) * tanhfast(gg);
                cst[b][j] = cn;
                float hv = sigf(og) * tanhfast(cn);
                hv01[u] = hv; cn01[u] = cn;
            }
            // packed 2xbf16 h store for the next step
            int hc0 = p * 16 + j0;
            unsigned pk = (unsigned)f2bf(hv01[0]) | ((unsigned)f2bf(hv01[1]) << 16);
            unsigned* dst = reinterpret_cast<unsigned*>(
                hexd + (size_t)(s & 1) * 16384 + (size_t)(hc0 >> 3) * 256 + b * 8 + (hc0 & 7));
            if (fast) {
                asm volatile("global_store_dword %0, %1, off sc0" :: "v"(dst), "v"(pk) : "memory");
            } else {
                __hip_atomic_store(dst, pk, __ATOMIC_RELAXED, __HIP_MEMORY_SCOPE_AGENT);
            }
        }

        // ---- publish: drain h stores, block barrier, single flag STORE ----
        asm volatile("s_waitcnt vmcnt(0)" ::: "memory");
        __syncthreads();   // sync#2: all waves' h stores acked; gates safe to reuse
        if (tid == 0) {
            if (fast) {
                unsigned sv = (unsigned)(s + 1);
                asm volatile("global_store_dword %0, %1, off sc0" :: "v"(flg + p), "v"(sv) : "memory");
            } else {
                __hip_atomic_store(flg + p, (unsigned)(s + 1), __ATOMIC_RELAXED, __HIP_MEMORY_SCOPE_AGENT);
            }
        }

        // ---- out stores AFTER publish (off the critical sync path) ----
#pragma unroll
        for (int u = 0; u < 2; ++u) {
            int hc = p * 16 + j0 + u;
            out[(size_t)b * (512 * 1024) + (size_t)t * 1024 + dir * 512 + hc] = hv01[u];
            if (s == 511) {
                out[16777216 + dir * 16384 + b * 512 + hc] = hv01[u];            // stacked_h
                out[16777216 + 32768 + dir * 16384 + b * 512 + hc] = cn01[u];    // stacked_c
            }
        }
    }
}

extern "C" void kernel_launch(void* const* d_in, const int* in_sizes, int n_in,
                              void* d_out, int out_size, void* d_ws, size_t ws_size,
                              hipStream_t stream) {
    const float* X     = (const float*)d_in[0];
    const float* Wih_f = (const float*)d_in[1];
    const float* Whh_f = (const float*)d_in[2];
    const float* bih_f = (const float*)d_in[3];
    const float* bhh_f = (const float*)d_in[4];
    const float* Wih_b = (const float*)d_in[5];
    const float* Whh_b = (const float*)d_in[6];
    const float* bih_b = (const float*)d_in[7];
    const float* bhh_b = (const float*)d_in[8];
    float* out = (float*)d_out;

    unsigned short* Xb   = (unsigned short*)((char*)d_ws + XB_OFF);
    unsigned short* h_ex = (unsigned short*)((char*)d_ws + HEX_OFF);
    unsigned*       flg  = (unsigned*)((char*)d_ws + CTR_OFF);

    // zero h_ex (h_{-1}=0) + flags + placement table
    hipMemsetAsync((char*)d_ws + HEX_OFF, 0, (128ull + 64ull) << 10, stream);
    k_xpose<<<8192, 256, 0, stream>>>(X, Xb);
    // 256 blocks (1/CU): round-robin puts (blockIdx&7)==d on XCD d.
    k_bilstm<<<256, 256, 0, stream>>>(Wih_f, Whh_f, bih_f, bhh_f,
                                      Wih_b, Whh_b, bih_b, bhh_b,
                                      Xb, h_ex, flg, out);
}

// Round 13
// 2501.339 us; speedup vs baseline: 1.1336x; 1.1336x over previous
//
#include <hip/hip_runtime.h>
#include <hip/hip_bf16.h>

// Problem dims
#define BSZ 32
#define SSZ 512
#define ISZ 512
#define HSZ 512
// ws layout (bytes)
#define XB_OFF   0ull                       // [S][64 kc][32 b][8] ushort (bf16 bits) = 16 MB
#define HEX_OFF  (16ull << 20)              // [2 dir][2 buf][64 kc][32 b][8] ushort = 128 KB
#define CTR_OFF  (HEX_OFF + (128ull << 10)) // flags: [dir] stride 2048 dwords; tab at dword 4096

typedef __attribute__((ext_vector_type(8)))  short short8;
typedef __attribute__((ext_vector_type(4)))  float f32x4;
typedef __attribute__((ext_vector_type(4)))  unsigned short us4;
typedef __attribute__((ext_vector_type(4)))  int i32x4;

__device__ __forceinline__ unsigned short f2bf(float f) {
    union { float f; unsigned u; } v; v.f = f;
    unsigned r = v.u + 0x7fffu + ((v.u >> 16) & 1u);   // RNE
    return (unsigned short)(r >> 16);
}

__device__ __forceinline__ float sigf(float x) { return 1.0f / (1.0f + __expf(-x)); }
__device__ __forceinline__ float tanhfast(float x) {
    float a = fabsf(x);
    float e = __expf(-2.0f * a);
    float t = (1.0f - e) / (1.0f + e);
    return x < 0.0f ? -t : t;
}

// X [B][S][I] fp32 -> Xb [t][kc][b][8] bf16-bits (MFMA A-fragment friendly layout)
__global__ void k_xpose(const float* __restrict__ X, unsigned short* __restrict__ Xb) {
    int idx = blockIdx.x * 256 + threadIdx.x;     // 2^21 threads total
    int i4 = idx & 127;                           // float4 index along I
    int t  = (idx >> 7) & 511;
    int b  = idx >> 16;
    float4 v = reinterpret_cast<const float4*>(X)[idx];
    us4 o = { f2bf(v.x), f2bf(v.y), f2bf(v.z), f2bf(v.w) };
    *reinterpret_cast<us4*>(Xb + (size_t)t * 16384 + (size_t)(i4 >> 1) * 256 + b * 8 + (i4 & 1) * 4) = o;
}

// SESSION-FINAL (= R9/R11, verified twice at 2426/2455 us dispatch):
// - 32 blocks/dir pinned to one XCD via blockIdx%8 placement (runtime-verified, with
//   agent-scope fallback): h exchange + flags run at L2 scope (sc0).
// - h-waves K-SPLIT the recurrence (wave2: K[0,256), wave3: K[256,512)) -> halves the
//   same-line L2 read hotspot on the h buffer (the one verified win besides scope).
// - The ALL-32 flag wait on one line + {drain -> barrier -> tid0 single flag store}
//   publish edge is a GLOBAL RE-SYNCHRONIZER: it keeps the 64 producer chains
//   phase-aligned each step. Twelve rounds of A/B showed ANY mutation (fan-out R8,
//   barrier removal R10, out-deferral R7, split wait R12, chunking R6) drops the
//   lockstep into a ~1.7x phase-split mode. Do not touch without new evidence.
__launch_bounds__(256, 1)
__global__ void k_bilstm(const float* __restrict__ Wih_f, const float* __restrict__ Whh_f,
                         const float* __restrict__ bih_f, const float* __restrict__ bhh_f,
                         const float* __restrict__ Wih_b, const float* __restrict__ Whh_b,
                         const float* __restrict__ bih_b, const float* __restrict__ bhh_b,
                         const unsigned short* __restrict__ Xb,
                         unsigned short* h_ex, unsigned* flags, float* __restrict__ out)
{
    const int tid = threadIdx.x;
    const int grp = blockIdx.x & 7;
    if (grp >= 2) return;                // 256 blocks: XCD0 = dir0, XCD1 = dir1
    const int dir = grp;
    const int p   = blockIdx.x >> 3;     // 0..31 : owns h-cols [16p, 16p+16)
    const int wv  = tid >> 6;
    const int ln  = tid & 63;
    const int kh  = wv >> 1;             // 0: x-projection, 1: h-recurrence
    const int sub = wv & 1;              // x: gate-pair ; h: K-half
    const int q   = ln >> 4;
    const int m15 = ln & 15;

    unsigned* tab = flags + 4096;
    {
        unsigned xcc;
        asm volatile("s_getreg_b32 %0, hwreg(20, 0, 32)" : "=s"(xcc));
        if (tid == 0)
            __hip_atomic_store(tab + dir * 32 + p, (xcc & 7u) + 1u,
                               __ATOMIC_RELAXED, __HIP_MEMORY_SCOPE_AGENT);
    }

    const float* Wih = dir ? Wih_b : Wih_f;
    const float* Whh = dir ? Whh_b : Whh_f;
    const float* bi  = dir ? bih_b : bih_f;
    const float* bh  = dir ? bhh_b : bhh_f;

    __shared__ float gates[3][32][67];   // 0: x (col-split), 1: h K-half0, 2: h K-half1
    __shared__ float cst[32][16];
    __shared__ float bias[64];
    __shared__ int   mode_sh;

    // ---- weights in registers for all 512 steps (128 VGPRs either role) ----
    short8 breg[32];
    if (kh == 0) {
        // x-wave: gate-pair sub (gates sub*2, sub*2+1), full K -> breg[ks*2+gg]
#pragma unroll
        for (int ks = 0; ks < 16; ++ks)
#pragma unroll
            for (int gg = 0; gg < 2; ++gg) {
                const float* wr = Wih + (size_t)((sub * 2 + gg) * 512 + p * 16 + m15) * 512
                                      + ks * 32 + q * 8;
                short8 bb;
#pragma unroll
                for (int j = 0; j < 8; ++j) bb[j] = (short)f2bf(wr[j]);
                breg[ks * 2 + gg] = bb;
            }
    } else {
        // h-wave: ALL 4 gates, K-half sub -> breg[ks*4+g], ks 0..7
#pragma unroll
        for (int ks = 0; ks < 8; ++ks)
#pragma unroll
            for (int g = 0; g < 4; ++g) {
                const float* wr = Whh + (size_t)(g * 512 + p * 16 + m15) * 512
                                      + sub * 256 + ks * 32 + q * 8;
                short8 bb;
#pragma unroll
                for (int j = 0; j < 8; ++j) bb[j] = (short)f2bf(wr[j]);
                breg[ks * 4 + g] = bb;
            }
    }

    if (tid < 64) {
        int c = tid;
        int gr = (c >> 4) * 512 + p * 16 + (c & 15);
        bias[c] = bi[gr] + bh[gr];
    }
    for (int i = tid; i < 512; i += 256) ((float*)cst)[i] = 0.0f;

    // ---- placement discovery (deadlock-free: every owner writes its slot) ----
    if (tid < 64) {
        const unsigned* tp = tab + dir * 32 + (tid & 31);
        unsigned v;
        do { v = __hip_atomic_load(tp, __ATOMIC_RELAXED, __HIP_MEMORY_SCOPE_AGENT); } while (v == 0u);
        unsigned ref = __shfl(v, 0);
        int same = (__ballot(v == ref) == ~0ull) ? 1 : 0;
        if (tid == 0) mode_sh = same;
    }
    __syncthreads();
    const int fast = mode_sh;

    unsigned* flg = flags + (size_t)dir * 2048;      // 32 dwords = 1 cache line per dir
    unsigned short* hexd = h_ex + (size_t)dir * 2 * 16384;

    int agent_poll = 0;

    for (int s = 0; s < 512; ++s) {
        const int t = dir ? (511 - s) : s;
        f32x4 acc[4][2];
#pragma unroll
        for (int g = 0; g < 4; ++g) { acc[g][0] = {0.f,0.f,0.f,0.f}; acc[g][1] = {0.f,0.f,0.f,0.f}; }

        if (kh == 0) {
            // ---- x-projection: no waiting ever; plain (L2-cacheable) loads ----
            const unsigned short* abase = Xb + (size_t)t * 16384;
#pragma unroll
            for (int ks = 0; ks < 16; ++ks) {
                const unsigned short* ap = abase + (size_t)(ks * 4 + q) * 256 + m15 * 8;
                short8 a0 = *reinterpret_cast<const short8*>(ap);
                short8 a1 = *reinterpret_cast<const short8*>(ap + 128);
                acc[0][0] = __builtin_amdgcn_mfma_f32_16x16x32_bf16(a0, breg[ks * 2 + 0], acc[0][0], 0, 0, 0);
                acc[1][0] = __builtin_amdgcn_mfma_f32_16x16x32_bf16(a0, breg[ks * 2 + 1], acc[1][0], 0, 0, 0);
                acc[0][1] = __builtin_amdgcn_mfma_f32_16x16x32_bf16(a1, breg[ks * 2 + 0], acc[0][1], 0, 0, 0);
                acc[1][1] = __builtin_amdgcn_mfma_f32_16x16x32_bf16(a1, breg[ks * 2 + 1], acc[1][1], 0, 0, 0);
            }
            // dump: plane 0, cols (sub*2+gg)*16 + m15
#pragma unroll
            for (int gg = 0; gg < 2; ++gg)
#pragma unroll
                for (int r = 0; r < 4; ++r) {
                    gates[0][q * 4 + r][(sub * 2 + gg) * 16 + m15]      = acc[gg][0][r];
                    gates[0][16 + q * 4 + r][(sub * 2 + gg) * 16 + m15] = acc[gg][1][r];
                }
        } else if (fast) {
            // ---- h-recurrence, XCD-local L2 path; K-half `sub` only (16KB) ----
            if (s > 0) {
                const unsigned* fp = flg + (ln & 31);
                if (!agent_poll) {
                    int spins = 0;
                    for (;;) {
                        unsigned v;
                        asm volatile("global_load_dword %0, %1, off sc0\n\t"
                                     "s_waitcnt vmcnt(0)"
                                     : "=&v"(v) : "v"(fp) : "memory");
                        if (__ballot((int)(v >= (unsigned)s)) == ~0ull) break;
                        if (++spins > 20000) { agent_poll = 1; break; }
                    }
                }
                if (agent_poll) {
                    for (;;) {
                        unsigned v = __hip_atomic_load(fp, __ATOMIC_RELAXED, __HIP_MEMORY_SCOPE_AGENT);
                        if (__ballot((int)(v >= (unsigned)s)) == ~0ull) break;
                    }
                }
                asm volatile("" ::: "memory");
            }
            const unsigned short* ab = hexd + (size_t)((s + 1) & 1) * 16384 + sub * 8192;
            i32x4 A0[8], A1[8];
#pragma unroll
            for (int ks = 0; ks < 8; ++ks) {
                const unsigned short* ap = ab + (size_t)(ks * 4 + q) * 256 + m15 * 8;
                asm volatile("global_load_dwordx4 %0, %2, off sc0\n\t"
                             "global_load_dwordx4 %1, %3, off sc0"
                             : "=&v"(A0[ks]), "=&v"(A1[ks])
                             : "v"(ap), "v"(ap + 128) : "memory");
            }
#pragma unroll
            for (int ks = 0; ks < 8; ++ks) {
                asm volatile("s_waitcnt vmcnt(%0)" :: "n"(14 - 2 * ks) : "memory");
                __builtin_amdgcn_sched_barrier(0);
                short8 a0 = __builtin_bit_cast(short8, A0[ks]);
                short8 a1 = __builtin_bit_cast(short8, A1[ks]);
#pragma unroll
                for (int g = 0; g < 4; ++g) {
                    acc[g][0] = __builtin_amdgcn_mfma_f32_16x16x32_bf16(a0, breg[ks * 4 + g], acc[g][0], 0, 0, 0);
                    acc[g][1] = __builtin_amdgcn_mfma_f32_16x16x32_bf16(a1, breg[ks * 4 + g], acc[g][1], 0, 0, 0);
                }
            }
            // dump: K-partial plane 1+sub, full 64-col width
#pragma unroll
            for (int g = 0; g < 4; ++g)
#pragma unroll
                for (int r = 0; r < 4; ++r) {
                    gates[1 + sub][q * 4 + r][g * 16 + m15]      = acc[g][0][r];
                    gates[1 + sub][16 + q * 4 + r][g * 16 + m15] = acc[g][1][r];
                }
        } else {
            // ---- h-recurrence, fallback agent/LLC path (K-split identically) ----
            if (s > 0) {
                const unsigned* fp = flg + (ln & 31);
                for (;;) {
                    unsigned v = __hip_atomic_load(fp, __ATOMIC_RELAXED, __HIP_MEMORY_SCOPE_AGENT);
                    if (__ballot((int)(v >= (unsigned)s)) == ~0ull) break;
                }
                asm volatile("" ::: "memory");
            }
            const unsigned* abase = reinterpret_cast<const unsigned*>(
                hexd + (size_t)((s + 1) & 1) * 16384 + sub * 8192);
#pragma unroll
            for (int ks = 0; ks < 8; ++ks) {
                const unsigned* ap = abase + ((ks * 4 + q) * 256 + m15 * 8) / 2;
                union { short8 s8; unsigned u[4]; } ua0, ua1;
#pragma unroll
                for (int w = 0; w < 4; ++w) {
                    ua0.u[w] = __hip_atomic_load(ap + w,      __ATOMIC_RELAXED, __HIP_MEMORY_SCOPE_AGENT);
                    ua1.u[w] = __hip_atomic_load(ap + 64 + w, __ATOMIC_RELAXED, __HIP_MEMORY_SCOPE_AGENT);
                }
#pragma unroll
                for (int g = 0; g < 4; ++g) {
                    acc[g][0] = __builtin_amdgcn_mfma_f32_16x16x32_bf16(ua0.s8, breg[ks * 4 + g], acc[g][0], 0, 0, 0);
                    acc[g][1] = __builtin_amdgcn_mfma_f32_16x16x32_bf16(ua1.s8, breg[ks * 4 + g], acc[g][1], 0, 0, 0);
                }
            }
#pragma unroll
            for (int g = 0; g < 4; ++g)
#pragma unroll
                for (int r = 0; r < 4; ++r) {
                    gates[1 + sub][q * 4 + r][g * 16 + m15]      = acc[g][0][r];
                    gates[1 + sub][16 + q * 4 + r][g * 16 + m15] = acc[g][1][r];
                }
        }

        __syncthreads();   // sync#1: all three plane dumps visible

        // ---- gate math: each thread handles (b, j0) and (b, j0+1); 3-plane sum ----
        int b  = tid >> 3;
        int j0 = (tid & 7) * 2;
        float hv01[2], cn01[2];
        {
#pragma unroll
            for (int u = 0; u < 2; ++u) {
                int j = j0 + u;
                float ig = gates[0][b][j]      + gates[1][b][j]      + gates[2][b][j]      + bias[j];
                float fg = gates[0][b][16 + j] + gates[1][b][16 + j] + gates[2][b][16 + j] + bias[16 + j];
                float gg = gates[0][b][32 + j] + gates[1][b][32 + j] + gates[2][b][32 + j] + bias[32 + j];
                float og = gates[0][b][48 + j] + gates[1][b][48 + j] + gates[2][b][48 + j] + bias[48 + j];
                float cn = sigf(fg) * cst[b][j] + sigf(ig) * tanhfast(gg);
                cst[b][j] = cn;
                float hv = sigf(og) * tanhfast(cn);
                hv01[u] = hv; cn01[u] = cn;
            }
            // packed 2xbf16 h store for the next step
            int hc0 = p * 16 + j0;
            unsigned pk = (unsigned)f2bf(hv01[0]) | ((unsigned)f2bf(hv01[1]) << 16);
            unsigned* dst = reinterpret_cast<unsigned*>(
                hexd + (size_t)(s & 1) * 16384 + (size_t)(hc0 >> 3) * 256 + b * 8 + (hc0 & 7));
            if (fast) {
                asm volatile("global_store_dword %0, %1, off sc0" :: "v"(dst), "v"(pk) : "memory");
            } else {
                __hip_atomic_store(dst, pk, __ATOMIC_RELAXED, __HIP_MEMORY_SCOPE_AGENT);
            }
        }

        // ---- publish: drain h stores, block barrier, single flag STORE ----
        asm volatile("s_waitcnt vmcnt(0)" ::: "memory");
        __syncthreads();   // sync#2: all waves' h stores acked; gates safe to reuse
        if (tid == 0) {
            if (fast) {
                unsigned sv = (unsigned)(s + 1);
                asm volatile("global_store_dword %0, %1, off sc0" :: "v"(flg + p), "v"(sv) : "memory");
            } else {
                __hip_atomic_store(flg + p, (unsigned)(s + 1), __ATOMIC_RELAXED, __HIP_MEMORY_SCOPE_AGENT);
            }
        }

        // ---- out stores AFTER publish (off the critical sync path) ----
#pragma unroll
        for (int u = 0; u < 2; ++u) {
            int hc = p * 16 + j0 + u;
            out[(size_t)b * (512 * 1024) + (size_t)t * 1024 + dir * 512 + hc] = hv01[u];
            if (s == 511) {
                out[16777216 + dir * 16384 + b * 512 + hc] = hv01[u];            // stacked_h
                out[16777216 + 32768 + dir * 16384 + b * 512 + hc] = cn01[u];    // stacked_c
            }
        }
    }
}

extern "C" void kernel_launch(void* const* d_in, const int* in_sizes, int n_in,
                              void* d_out, int out_size, void* d_ws, size_t ws_size,
                              hipStream_t stream) {
    const float* X     = (const float*)d_in[0];
    const float* Wih_f = (const float*)d_in[1];
    const float* Whh_f = (const float*)d_in[2];
    const float* bih_f = (const float*)d_in[3];
    const float* bhh_f = (const float*)d_in[4];
    const float* Wih_b = (const float*)d_in[5];
    const float* Whh_b = (const float*)d_in[6];
    const float* bih_b = (const float*)d_in[7];
    const float* bhh_b = (const float*)d_in[8];
    float* out = (float*)d_out;

    unsigned short* Xb   = (unsigned short*)((char*)d_ws + XB_OFF);
    unsigned short* h_ex = (unsigned short*)((char*)d_ws + HEX_OFF);
    unsigned*       flg  = (unsigned*)((char*)d_ws + CTR_OFF);

    // zero h_ex (h_{-1}=0) + flags + placement table
    hipMemsetAsync((char*)d_ws + HEX_OFF, 0, (128ull + 64ull) << 10, stream);
    k_xpose<<<8192, 256, 0, stream>>>(X, Xb);
    // 256 blocks (1/CU): round-robin puts (blockIdx&7)==d on XCD d.
    k_bilstm<<<256, 256, 0, stream>>>(Wih_f, Whh_f, bih_f, bhh_f,
                                      Wih_b, Whh_b, bih_b, bhh_b,
                                      Xb, h_ex, flg, out);
}

// Round 14
// 2485.648 us; speedup vs baseline: 1.1408x; 1.0063x over previous
//
#include <hip/hip_runtime.h>
#include <hip/hip_bf16.h>

// Problem dims
#define BSZ 32
#define SSZ 512
#define ISZ 512
#define HSZ 512
// ws layout (bytes)
#define XB_OFF   0ull                       // [S][64 kc][32 b][8] ushort (bf16 bits) = 16 MB
#define HEX_OFF  (16ull << 20)              // [2 dir][2 buf][64 kc][32 b][8] ushort = 128 KB
#define CTR_OFF  (HEX_OFF + (128ull << 10)) // flags: [dir] stride 2048 dwords; tab at dword 4096

typedef __attribute__((ext_vector_type(8)))  short short8;
typedef __attribute__((ext_vector_type(4)))  float f32x4;
typedef __attribute__((ext_vector_type(4)))  unsigned short us4;
typedef __attribute__((ext_vector_type(4)))  int i32x4;

__device__ __forceinline__ unsigned short f2bf(float f) {
    union { float f; unsigned u; } v; v.f = f;
    unsigned r = v.u + 0x7fffu + ((v.u >> 16) & 1u);   // RNE
    return (unsigned short)(r >> 16);
}

__device__ __forceinline__ float sigf(float x) { return 1.0f / (1.0f + __expf(-x)); }
__device__ __forceinline__ float tanhfast(float x) {
    float a = fabsf(x);
    float e = __expf(-2.0f * a);
    float t = (1.0f - e) / (1.0f + e);
    return x < 0.0f ? -t : t;
}

// X [B][S][I] fp32 -> Xb [t][kc][b][8] bf16-bits (MFMA A-fragment friendly layout)
__global__ void k_xpose(const float* __restrict__ X, unsigned short* __restrict__ Xb) {
    int idx = blockIdx.x * 256 + threadIdx.x;     // 2^21 threads total
    int i4 = idx & 127;                           // float4 index along I
    int t  = (idx >> 7) & 511;
    int b  = idx >> 16;
    float4 v = reinterpret_cast<const float4*>(X)[idx];
    us4 o = { f2bf(v.x), f2bf(v.y), f2bf(v.z), f2bf(v.w) };
    *reinterpret_cast<us4*>(Xb + (size_t)t * 16384 + (size_t)(i4 >> 1) * 256 + b * 8 + (i4 & 1) * 4) = o;
}

// Floor structure (= R9/R11/R13, verified 3x at 2427-2455 us dispatch) + ONE addition:
// h-waves raise wave priority (s_setprio 1) ONLY during their poll+load+MFMA phase,
// dropping back to 0 before the gate-dump / barrier-joined phases. Pure scheduler
// hint — zero memory-op or ordering changes, so the publish/poll edge (proven
// fragile: R7/R8/R10/R12 all slow-moded) is byte-identical to the verified floor.
// - 32 blocks/dir pinned to one XCD via blockIdx%8 (runtime-verified, agent fallback)
// - h-waves K-SPLIT the recurrence (wave2: K[0,256), wave3: K[256,512))
// - ALL-32 flag wait on one line = global re-synchronizer; do not touch.
__launch_bounds__(256, 1)
__global__ void k_bilstm(const float* __restrict__ Wih_f, const float* __restrict__ Whh_f,
                         const float* __restrict__ bih_f, const float* __restrict__ bhh_f,
                         const float* __restrict__ Wih_b, const float* __restrict__ Whh_b,
                         const float* __restrict__ bih_b, const float* __restrict__ bhh_b,
                         const unsigned short* __restrict__ Xb,
                         unsigned short* h_ex, unsigned* flags, float* __restrict__ out)
{
    const int tid = threadIdx.x;
    const int grp = blockIdx.x & 7;
    if (grp >= 2) return;                // 256 blocks: XCD0 = dir0, XCD1 = dir1
    const int dir = grp;
    const int p   = blockIdx.x >> 3;     // 0..31 : owns h-cols [16p, 16p+16)
    const int wv  = tid >> 6;
    const int ln  = tid & 63;
    const int kh  = wv >> 1;             // 0: x-projection, 1: h-recurrence
    const int sub = wv & 1;              // x: gate-pair ; h: K-half
    const int q   = ln >> 4;
    const int m15 = ln & 15;

    unsigned* tab = flags + 4096;
    {
        unsigned xcc;
        asm volatile("s_getreg_b32 %0, hwreg(20, 0, 32)" : "=s"(xcc));
        if (tid == 0)
            __hip_atomic_store(tab + dir * 32 + p, (xcc & 7u) + 1u,
                               __ATOMIC_RELAXED, __HIP_MEMORY_SCOPE_AGENT);
    }

    const float* Wih = dir ? Wih_b : Wih_f;
    const float* Whh = dir ? Whh_b : Whh_f;
    const float* bi  = dir ? bih_b : bih_f;
    const float* bh  = dir ? bhh_b : bhh_f;

    __shared__ float gates[3][32][67];   // 0: x (col-split), 1: h K-half0, 2: h K-half1
    __shared__ float cst[32][16];
    __shared__ float bias[64];
    __shared__ int   mode_sh;

    // ---- weights in registers for all 512 steps (128 VGPRs either role) ----
    short8 breg[32];
    if (kh == 0) {
        // x-wave: gate-pair sub (gates sub*2, sub*2+1), full K -> breg[ks*2+gg]
#pragma unroll
        for (int ks = 0; ks < 16; ++ks)
#pragma unroll
            for (int gg = 0; gg < 2; ++gg) {
                const float* wr = Wih + (size_t)((sub * 2 + gg) * 512 + p * 16 + m15) * 512
                                      + ks * 32 + q * 8;
                short8 bb;
#pragma unroll
                for (int j = 0; j < 8; ++j) bb[j] = (short)f2bf(wr[j]);
                breg[ks * 2 + gg] = bb;
            }
    } else {
        // h-wave: ALL 4 gates, K-half sub -> breg[ks*4+g], ks 0..7
#pragma unroll
        for (int ks = 0; ks < 8; ++ks)
#pragma unroll
            for (int g = 0; g < 4; ++g) {
                const float* wr = Whh + (size_t)(g * 512 + p * 16 + m15) * 512
                                      + sub * 256 + ks * 32 + q * 8;
                short8 bb;
#pragma unroll
                for (int j = 0; j < 8; ++j) bb[j] = (short)f2bf(wr[j]);
                breg[ks * 4 + g] = bb;
            }
    }

    if (tid < 64) {
        int c = tid;
        int gr = (c >> 4) * 512 + p * 16 + (c & 15);
        bias[c] = bi[gr] + bh[gr];
    }
    for (int i = tid; i < 512; i += 256) ((float*)cst)[i] = 0.0f;

    // ---- placement discovery (deadlock-free: every owner writes its slot) ----
    if (tid < 64) {
        const unsigned* tp = tab + dir * 32 + (tid & 31);
        unsigned v;
        do { v = __hip_atomic_load(tp, __ATOMIC_RELAXED, __HIP_MEMORY_SCOPE_AGENT); } while (v == 0u);
        unsigned ref = __shfl(v, 0);
        int same = (__ballot(v == ref) == ~0ull) ? 1 : 0;
        if (tid == 0) mode_sh = same;
    }
    __syncthreads();
    const int fast = mode_sh;

    unsigned* flg = flags + (size_t)dir * 2048;      // 32 dwords = 1 cache line per dir
    unsigned short* hexd = h_ex + (size_t)dir * 2 * 16384;

    int agent_poll = 0;

    for (int s = 0; s < 512; ++s) {
        const int t = dir ? (511 - s) : s;
        f32x4 acc[4][2];
#pragma unroll
        for (int g = 0; g < 4; ++g) { acc[g][0] = {0.f,0.f,0.f,0.f}; acc[g][1] = {0.f,0.f,0.f,0.f}; }

        if (kh == 0) {
            // ---- x-projection: no waiting ever; plain (L2-cacheable) loads ----
            const unsigned short* abase = Xb + (size_t)t * 16384;
#pragma unroll
            for (int ks = 0; ks < 16; ++ks) {
                const unsigned short* ap = abase + (size_t)(ks * 4 + q) * 256 + m15 * 8;
                short8 a0 = *reinterpret_cast<const short8*>(ap);
                short8 a1 = *reinterpret_cast<const short8*>(ap + 128);
                acc[0][0] = __builtin_amdgcn_mfma_f32_16x16x32_bf16(a0, breg[ks * 2 + 0], acc[0][0], 0, 0, 0);
                acc[1][0] = __builtin_amdgcn_mfma_f32_16x16x32_bf16(a0, breg[ks * 2 + 1], acc[1][0], 0, 0, 0);
                acc[0][1] = __builtin_amdgcn_mfma_f32_16x16x32_bf16(a1, breg[ks * 2 + 0], acc[0][1], 0, 0, 0);
                acc[1][1] = __builtin_amdgcn_mfma_f32_16x16x32_bf16(a1, breg[ks * 2 + 1], acc[1][1], 0, 0, 0);
            }
            // dump: plane 0, cols (sub*2+gg)*16 + m15
#pragma unroll
            for (int gg = 0; gg < 2; ++gg)
#pragma unroll
                for (int r = 0; r < 4; ++r) {
                    gates[0][q * 4 + r][(sub * 2 + gg) * 16 + m15]      = acc[gg][0][r];
                    gates[0][16 + q * 4 + r][(sub * 2 + gg) * 16 + m15] = acc[gg][1][r];
                }
        } else if (fast) {
            // ---- h-recurrence, XCD-local L2 path; K-half `sub` only (16KB) ----
            // Critical chain of the whole lockstep: boost issue priority for the
            // poll+load+MFMA window (x-waves have slack here), drop before dump.
            __builtin_amdgcn_s_setprio(1);
            if (s > 0) {
                const unsigned* fp = flg + (ln & 31);
                if (!agent_poll) {
                    int spins = 0;
                    for (;;) {
                        unsigned v;
                        asm volatile("global_load_dword %0, %1, off sc0\n\t"
                                     "s_waitcnt vmcnt(0)"
                                     : "=&v"(v) : "v"(fp) : "memory");
                        if (__ballot((int)(v >= (unsigned)s)) == ~0ull) break;
                        if (++spins > 20000) { agent_poll = 1; break; }
                    }
                }
                if (agent_poll) {
                    for (;;) {
                        unsigned v = __hip_atomic_load(fp, __ATOMIC_RELAXED, __HIP_MEMORY_SCOPE_AGENT);
                        if (__ballot((int)(v >= (unsigned)s)) == ~0ull) break;
                    }
                }
                asm volatile("" ::: "memory");
            }
            const unsigned short* ab = hexd + (size_t)((s + 1) & 1) * 16384 + sub * 8192;
            i32x4 A0[8], A1[8];
#pragma unroll
            for (int ks = 0; ks < 8; ++ks) {
                const unsigned short* ap = ab + (size_t)(ks * 4 + q) * 256 + m15 * 8;
                asm volatile("global_load_dwordx4 %0, %2, off sc0\n\t"
                             "global_load_dwordx4 %1, %3, off sc0"
                             : "=&v"(A0[ks]), "=&v"(A1[ks])
                             : "v"(ap), "v"(ap + 128) : "memory");
            }
#pragma unroll
            for (int ks = 0; ks < 8; ++ks) {
                asm volatile("s_waitcnt vmcnt(%0)" :: "n"(14 - 2 * ks) : "memory");
                __builtin_amdgcn_sched_barrier(0);
                short8 a0 = __builtin_bit_cast(short8, A0[ks]);
                short8 a1 = __builtin_bit_cast(short8, A1[ks]);
#pragma unroll
                for (int g = 0; g < 4; ++g) {
                    acc[g][0] = __builtin_amdgcn_mfma_f32_16x16x32_bf16(a0, breg[ks * 4 + g], acc[g][0], 0, 0, 0);
                    acc[g][1] = __builtin_amdgcn_mfma_f32_16x16x32_bf16(a1, breg[ks * 4 + g], acc[g][1], 0, 0, 0);
                }
            }
            __builtin_amdgcn_s_setprio(0);   // parity restored before barrier-joined phases
            // dump: K-partial plane 1+sub, full 64-col width
#pragma unroll
            for (int g = 0; g < 4; ++g)
#pragma unroll
                for (int r = 0; r < 4; ++r) {
                    gates[1 + sub][q * 4 + r][g * 16 + m15]      = acc[g][0][r];
                    gates[1 + sub][16 + q * 4 + r][g * 16 + m15] = acc[g][1][r];
                }
        } else {
            // ---- h-recurrence, fallback agent/LLC path (K-split identically) ----
            if (s > 0) {
                const unsigned* fp = flg + (ln & 31);
                for (;;) {
                    unsigned v = __hip_atomic_load(fp, __ATOMIC_RELAXED, __HIP_MEMORY_SCOPE_AGENT);
                    if (__ballot((int)(v >= (unsigned)s)) == ~0ull) break;
                }
                asm volatile("" ::: "memory");
            }
            const unsigned* abase = reinterpret_cast<const unsigned*>(
                hexd + (size_t)((s + 1) & 1) * 16384 + sub * 8192);
#pragma unroll
            for (int ks = 0; ks < 8; ++ks) {
                const unsigned* ap = abase + ((ks * 4 + q) * 256 + m15 * 8) / 2;
                union { short8 s8; unsigned u[4]; } ua0, ua1;
#pragma unroll
                for (int w = 0; w < 4; ++w) {
                    ua0.u[w] = __hip_atomic_load(ap + w,      __ATOMIC_RELAXED, __HIP_MEMORY_SCOPE_AGENT);
                    ua1.u[w] = __hip_atomic_load(ap + 64 + w, __ATOMIC_RELAXED, __HIP_MEMORY_SCOPE_AGENT);
                }
#pragma unroll
                for (int g = 0; g < 4; ++g) {
                    acc[g][0] = __builtin_amdgcn_mfma_f32_16x16x32_bf16(ua0.s8, breg[ks * 4 + g], acc[g][0], 0, 0, 0);
                    acc[g][1] = __builtin_amdgcn_mfma_f32_16x16x32_bf16(ua1.s8, breg[ks * 4 + g], acc[g][1], 0, 0, 0);
                }
            }
#pragma unroll
            for (int g = 0; g < 4; ++g)
#pragma unroll
                for (int r = 0; r < 4; ++r) {
                    gates[1 + sub][q * 4 + r][g * 16 + m15]      = acc[g][0][r];
                    gates[1 + sub][16 + q * 4 + r][g * 16 + m15] = acc[g][1][r];
                }
        }

        __syncthreads();   // sync#1: all three plane dumps visible

        // ---- gate math: each thread handles (b, j0) and (b, j0+1); 3-plane sum ----
        int b  = tid >> 3;
        int j0 = (tid & 7) * 2;
        float hv01[2], cn01[2];
        {
#pragma unroll
            for (int u = 0; u < 2; ++u) {
                int j = j0 + u;
                float ig = gates[0][b][j]      + gates[1][b][j]      + gates[2][b][j]      + bias[j];
                float fg = gates[0][b][16 + j] + gates[1][b][16 + j] + gates[2][b][16 + j] + bias[16 + j];
                float gg = gates[0][b][32 + j] + gates[1][b][32 + j] + gates[2][b][32 + j] + bias[32 + j];
                float og = gates[0][b][48 + j] + gates[1][b][48 + j] + gates[2][b][48 + j] + bias[48 + j];
                float cn = sigf(fg) * cst[b][j] + sigf(ig) * tanhfast(gg);
                cst[b][j] = cn;
                float hv = sigf(og) * tanhfast(cn);
                hv01[u] = hv; cn01[u] = cn;
            }
            // packed 2xbf16 h store for the next step
            int hc0 = p * 16 + j0;
            unsigned pk = (unsigned)f2bf(hv01[0]) | ((unsigned)f2bf(hv01[1]) << 16);
            unsigned* dst = reinterpret_cast<unsigned*>(
                hexd + (size_t)(s & 1) * 16384 + (size_t)(hc0 >> 3) * 256 + b * 8 + (hc0 & 7));
            if (fast) {
                asm volatile("global_store_dword %0, %1, off sc0" :: "v"(dst), "v"(pk) : "memory");
            } else {
                __hip_atomic_store(dst, pk, __ATOMIC_RELAXED, __HIP_MEMORY_SCOPE_AGENT);
            }
        }

        // ---- publish: drain h stores, block barrier, single flag STORE ----
        asm volatile("s_waitcnt vmcnt(0)" ::: "memory");
        __syncthreads();   // sync#2: all waves' h stores acked; gates safe to reuse
        if (tid == 0) {
            if (fast) {
                unsigned sv = (unsigned)(s + 1);
                asm volatile("global_store_dword %0, %1, off sc0" :: "v"(flg + p), "v"(sv) : "memory");
            } else {
                __hip_atomic_store(flg + p, (unsigned)(s + 1), __ATOMIC_RELAXED, __HIP_MEMORY_SCOPE_AGENT);
            }
        }

        // ---- out stores AFTER publish (off the critical sync path) ----
#pragma unroll
        for (int u = 0; u < 2; ++u) {
            int hc = p * 16 + j0 + u;
            out[(size_t)b * (512 * 1024) + (size_t)t * 1024 + dir * 512 + hc] = hv01[u];
            if (s == 511) {
                out[16777216 + dir * 16384 + b * 512 + hc] = hv01[u];            // stacked_h
                out[16777216 + 32768 + dir * 16384 + b * 512 + hc] = cn01[u];    // stacked_c
            }
        }
    }
}

extern "C" void kernel_launch(void* const* d_in, const int* in_sizes, int n_in,
                              void* d_out, int out_size, void* d_ws, size_t ws_size,
                              hipStream_t stream) {
    const float* X     = (const float*)d_in[0];
    const float* Wih_f = (const float*)d_in[1];
    const float* Whh_f = (const float*)d_in[2];
    const float* bih_f = (const float*)d_in[3];
    const float* bhh_f = (const float*)d_in[4];
    const float* Wih_b = (const float*)d_in[5];
    const float* Whh_b = (const float*)d_in[6];
    const float* bih_b = (const float*)d_in[7];
    const float* bhh_b = (const float*)d_in[8];
    float* out = (float*)d_out;

    unsigned short* Xb   = (unsigned short*)((char*)d_ws + XB_OFF);
    unsigned short* h_ex = (unsigned short*)((char*)d_ws + HEX_OFF);
    unsigned*       flg  = (unsigned*)((char*)d_ws + CTR_OFF);

    // zero h_ex (h_{-1}=0) + flags + placement table
    hipMemsetAsync((char*)d_ws + HEX_OFF, 0, (128ull + 64ull) << 10, stream);
    k_xpose<<<8192, 256, 0, stream>>>(X, Xb);
    // 256 blocks (1/CU): round-robin puts (blockIdx&7)==d on XCD d.
    k_bilstm<<<256, 256, 0, stream>>>(Wih_f, Whh_f, bih_f, bhh_f,
                                      Wih_b, Whh_b, bih_b, bhh_b,
                                      Xb, h_ex, flg, out);
}